// Round 4
// baseline (3429.241 us; speedup 1.0000x reference)
//
#include <hip/hip_runtime.h>
#include <hip/hip_bf16.h>

#define EMB 768
#define HID 3072
#define HID2 6144
#define NE 8
#define TOK 16384    // B*N = 8*2048
#define SLOTS 32768  // TOK * top-2
#define SLACK 256    // tail-read slack rows (M-tile 256 may overrun by 255)
#define MAXTILES 136 // max active M-tiles: 128 + (NE-1) partials

typedef __attribute__((ext_vector_type(8))) short bf16x8;
typedef __attribute__((ext_vector_type(4))) float f32x4;

__device__ __forceinline__ unsigned short bfbits(float f) {
  __hip_bfloat16 h = __float2bfloat16(f);
  return __builtin_bit_cast(unsigned short, h);
}

// ---------------- init / gating / routing ----------------

__global__ void k_init(int* counts, int* fill) {
  if (threadIdx.x < NE) { counts[threadIdx.x] = 0; fill[threadIdx.x] = 0; }
}

__global__ __launch_bounds__(256) void k_gating(
    const float* __restrict__ x, const float* __restrict__ Wg,
    const float* __restrict__ bg, int* __restrict__ eidx,
    float* __restrict__ gates, int* __restrict__ counts)
{
  const int wave = threadIdx.x >> 6, lane = threadIdx.x & 63;
  const int t = blockIdx.x * 4 + wave;
  const float* xr = x + (size_t)t * EMB;
  float p[NE];
#pragma unroll
  for (int e = 0; e < NE; ++e) p[e] = 0.f;
  for (int k = lane; k < EMB; k += 64) {
    const float xv = xr[k];
    const float* wr = Wg + (size_t)k * NE;
#pragma unroll
    for (int e = 0; e < NE; ++e) p[e] += xv * wr[e];
  }
#pragma unroll
  for (int e = 0; e < NE; ++e) {
#pragma unroll
    for (int o = 32; o > 0; o >>= 1) p[e] += __shfl_xor(p[e], o);
    p[e] += bg[e];
  }
  float v0 = -1e30f, v1 = -1e30f; int i0 = 0, i1 = 0;
#pragma unroll
  for (int e = 0; e < NE; ++e) {
    const float v = p[e];
    if (v > v0)      { v1 = v0; i1 = i0; v0 = v; i0 = e; }
    else if (v > v1) { v1 = v;  i1 = e; }
  }
  const float ex = expf(v1 - v0);
  const float g0 = 1.f / (1.f + ex);
  const float g1 = 1.f - g0;
  if (lane == 0) {
    eidx[2*t] = i0; eidx[2*t+1] = i1;
    gates[2*t] = g0; gates[2*t+1] = g1;
    atomicAdd(&counts[i0], 1);
    atomicAdd(&counts[i1], 1);
  }
}

// offsets + compact (expert, m-tile) map so GEMM grid.y has ~no empty blocks
__global__ void k_offsets(const int* __restrict__ counts, int* __restrict__ offsets,
                          int* __restrict__ tmap)
{
  offsets[0] = 0;
  int idx = 0;
  for (int e = 0; e < NE; ++e) {
    offsets[e+1] = offsets[e] + counts[e];
    const int nt = (counts[e] + 255) >> 8;
    for (int i = 0; i < nt; ++i) tmap[idx++] = (e << 16) | i;
  }
  for (; idx < MAXTILES; ++idx) tmap[idx] = -1;
}

__global__ void k_route(const int* __restrict__ eidx, int* __restrict__ fill,
                        const int* __restrict__ offsets, int* __restrict__ route_tok,
                        int* __restrict__ slot_of)
{
  const int t = blockIdx.x * 256 + threadIdx.x;
  if (t >= TOK) return;
#pragma unroll
  for (int k = 0; k < 2; ++k) {
    const int e = eidx[2*t + k];
    const int pos = atomicAdd(&fill[e], 1);
    const int slot = offsets[e] + pos;
    route_tok[slot] = t;
    slot_of[2*t + k] = slot;
  }
}

__global__ void k_gather(const float* __restrict__ x, const int* __restrict__ route_tok,
                         __hip_bfloat16* __restrict__ xg)
{
  const int s = blockIdx.x;
  const int t = route_tok[s];
  const float4 v = ((const float4*)(x + (size_t)t * EMB))[threadIdx.x];
  ushort4 u;
  u.x = bfbits(v.x); u.y = bfbits(v.y); u.z = bfbits(v.z); u.w = bfbits(v.w);
  *(ushort4*)((unsigned short*)xg + (size_t)s * EMB + threadIdx.x * 4) = u;
}

// fp32 [K,N] -> bf16 [N,K]  (per expert, LDS-tiled transpose)
__global__ void k_transpose(const float* __restrict__ W, __hip_bfloat16* __restrict__ Wt,
                            int K, int N)
{
  __shared__ float tile[32][33];
  const int e = blockIdx.z;
  const float* Wp = W + (size_t)e * K * N;
  __hip_bfloat16* Wtp = Wt + (size_t)e * K * N;
  const int n0 = blockIdx.x * 32, k0 = blockIdx.y * 32;
  for (int r = threadIdx.y; r < 32; r += 8)
    tile[r][threadIdx.x] = Wp[(size_t)(k0 + r) * N + n0 + threadIdx.x];
  __syncthreads();
  for (int r = threadIdx.y; r < 32; r += 8)
    Wtp[(size_t)(n0 + r) * K + k0 + threadIdx.x] = __float2bfloat16(tile[threadIdx.x][r]);
}

// ---------------- 256x128 2-phase MFMA GEMM, 2 blocks/CU ----------------
// A: bf16 [slots, K] (per-expert segments); Bt: bf16 [NE, N, K].
// BM=256, BN=128, BK=32, 4 waves (2M x 2N), per-wave 128x64 C.
// LDS 48 KiB: slot(24KB) = [A 16KB (256r x 64B)][B 8KB (128r x 64B)], 2 slots.
// Row-XOR swizzle for 64B rows: byte ^= ((row>>1)&3)<<4  (row parity supplies
// bank bit 4 via 16*row mod 32; row>>1 spreads the 4 16B slots) -> each bank
// hit exactly 2x per quarter-wave = conflict-free. Applied on global SOURCE
// (linear global_load_lds dest) + ds_read addr.

#define BARRIER() asm volatile("s_barrier" ::: "memory")

template<bool GELU, bool OUTBF>
__global__ __launch_bounds__(256, 2) void ffn_gemm2(
    const __hip_bfloat16* __restrict__ A,
    const __hip_bfloat16* __restrict__ Bt,
    const float* __restrict__ bias,
    void* __restrict__ Cout,
    const int* __restrict__ counts,
    const int* __restrict__ offsets,
    const int* __restrict__ tmap,
    int K, int N)
{
  const int me = tmap[blockIdx.y];
  if (me < 0) return;
  const int e  = me >> 16;
  const int m0 = (me & 0xffff) * 256;
  const int cnt = counts[e];
  const int seg = offsets[e];
  const int n0 = blockIdx.x * 128;

  __shared__ char lds[49152];

  const int tid = threadIdx.x;
  const int wave = tid >> 6, lane = tid & 63;
  const int wm = wave >> 1, wn = wave & 1;

  const size_t KB = (size_t)K * 2;           // global row stride bytes
  const char* Ag = (const char*)(A + (size_t)(seg + m0) * K);
  const char* Bg = (const char*)(Bt + (size_t)e * N * K + (size_t)n0 * K);

  // staging coords: one gload batch = 64 rows x 64 B; dest linear tid*16
  const int s_r  = tid >> 2;                                    // 0..63
  const int s_cb = ((tid & 3) * 16) ^ (((s_r >> 1) & 3) << 4);  // src pre-swizzle

  auto glds = [&](const char* src, int ldst) {
    __builtin_amdgcn_global_load_lds(
        (const __attribute__((address_space(1))) void*)src,
        (__attribute__((address_space(3))) void*)(lds + ldst + tid * 16), 16, 0, 0);
  };
  // A tile: 256 rows -> 4 gloads; B tile: 128 rows -> 2 gloads
  auto stageA = [&](int kbyte, int slotbase) {
    const char* s = Ag + (size_t)s_r * KB + kbyte + s_cb;
    glds(s,                 slotbase);
    glds(s +  64 * KB,      slotbase + 4096);
    glds(s + 128 * KB,      slotbase + 8192);
    glds(s + 192 * KB,      slotbase + 12288);
  };
  auto stageB = [&](int kbyte, int slotbase) {
    const char* s = Bg + (size_t)s_r * KB + kbyte + s_cb;
    glds(s,            slotbase + 16384);
    glds(s + 64 * KB,  slotbase + 16384 + 4096);
  };

  // fragment read offsets (row ^ swizzle folded into constants)
  const int fr   = lane & 15;
  const int coff = ((lane >> 4) * 16) ^ (((fr >> 1) & 3) << 4);
  const int aoff = (wm * 128 + fr) * 64 + coff;            // + m*1024
  const int boff = 16384 + (wn * 64 + fr) * 64 + coff;     // + n*1024

  f32x4 acc[8][4];
#pragma unroll
  for (int i = 0; i < 8; ++i)
#pragma unroll
    for (int j = 0; j < 4; ++j)
      acc[i][j] = (f32x4){0.f, 0.f, 0.f, 0.f};

  const int KT = K >> 5;                                   // BK=32 -> 64 bytes/step

  // ---- prologue: A(t0)+B(t0)->slot0, B(t1)->slot1 ; keep B(t1) in flight
  stageA(0, 0);
  stageB(0, 0);
  stageB(KT > 1 ? 64 : 0, 24576);
  asm volatile("s_waitcnt vmcnt(2)" ::: "memory");
  __builtin_amdgcn_sched_barrier(0);
  BARRIER();

  bf16x8 a[4], b[4];

  for (int kt = 0; kt < KT; ++kt) {
    const int slot = kt & 1;
    const int sb   = slot * 24576;
    const int kbA  = (kt + 1 < KT ? kt + 1 : KT - 1) * 64;
    const int kbB  = (kt + 2 < KT ? kt + 2 : KT - 1) * 64;

    // ---- phase 1: read a[0..3], b[0..3]; stage A(t+1)->slot^1; MFMA m0-3
#pragma unroll
    for (int m = 0; m < 4; ++m)
      a[m] = *(const bf16x8*)(lds + sb + aoff + m * 1024);
#pragma unroll
    for (int n = 0; n < 4; ++n)
      b[n] = *(const bf16x8*)(lds + sb + boff + n * 1024);
    stageA(kbA, sb ^ 24576);
    BARRIER();
    asm volatile("s_waitcnt lgkmcnt(0)" ::: "memory");
    __builtin_amdgcn_sched_barrier(0);
    __builtin_amdgcn_s_setprio(1);
#pragma unroll
    for (int m = 0; m < 4; ++m)
#pragma unroll
      for (int n = 0; n < 4; ++n)
        acc[m][n] = __builtin_amdgcn_mfma_f32_16x16x32_bf16(a[m], b[n], acc[m][n], 0, 0, 0);
    __builtin_amdgcn_s_setprio(0);
    BARRIER();

    // ---- phase 2: read a[4..7]; stage B(t+2)->current slot; vmcnt(2); MFMA m4-7
#pragma unroll
    for (int m = 0; m < 4; ++m)
      a[m] = *(const bf16x8*)(lds + sb + aoff + (m + 4) * 1024);
    stageB(kbB, sb);
    asm volatile("s_waitcnt vmcnt(2)" ::: "memory");
    __builtin_amdgcn_sched_barrier(0);
    BARRIER();
    asm volatile("s_waitcnt lgkmcnt(0)" ::: "memory");
    __builtin_amdgcn_sched_barrier(0);
    __builtin_amdgcn_s_setprio(1);
#pragma unroll
    for (int m = 0; m < 4; ++m)
#pragma unroll
      for (int n = 0; n < 4; ++n)
        acc[m + 4][n] = __builtin_amdgcn_mfma_f32_16x16x32_bf16(a[m], b[n], acc[m + 4][n], 0, 0, 0);
    __builtin_amdgcn_s_setprio(0);
    BARRIER();
  }

  // ---- epilogue: C/D map col=lane&15, row=(lane>>4)*4+r  [m89-verified]
#pragma unroll
  for (int mf = 0; mf < 8; ++mf) {
    const int gmb = m0 + wm * 128 + mf * 16 + (lane >> 4) * 4;
#pragma unroll
    for (int nf = 0; nf < 4; ++nf) {
      const int gcol = n0 + wn * 64 + nf * 16 + fr;
      const float bv = bias[(size_t)e * N + gcol];
#pragma unroll
      for (int r = 0; r < 4; ++r) {
        const int gm = gmb + r;
        if (gm < cnt) {
          float v = acc[mf][nf][r] + bv;
          if (GELU) v = 0.5f * v * (1.0f + erff(v * 0.70710678118654752f));
          if (OUTBF)
            ((__hip_bfloat16*)Cout)[(size_t)(seg + gm) * N + gcol] = __float2bfloat16(v);
          else
            ((float*)Cout)[(size_t)(seg + gm) * N + gcol] = v;
        }
      }
    }
  }
}

// out[t] = g0*y[slot0] + g1*y[slot1]
__global__ void k_combine(const float* __restrict__ ybuf, const int* __restrict__ slot_of,
                          const float* __restrict__ gates, float* __restrict__ out)
{
  const int t = blockIdx.x;
  const int s0 = slot_of[2*t], s1 = slot_of[2*t+1];
  const float g0 = gates[2*t], g1 = gates[2*t+1];
  const float4 a = ((const float4*)(ybuf + (size_t)s0 * EMB))[threadIdx.x];
  const float4 b = ((const float4*)(ybuf + (size_t)s1 * EMB))[threadIdx.x];
  float4 o;
  o.x = g0 * a.x + g1 * b.x;
  o.y = g0 * a.y + g1 * b.y;
  o.z = g0 * a.z + g1 * b.z;
  o.w = g0 * a.w + g1 * b.w;
  ((float4*)(out + (size_t)t * EMB))[threadIdx.x] = o;
}

// ---------------- launch ----------------

extern "C" void kernel_launch(void* const* d_in, const int* in_sizes, int n_in,
                              void* d_out, int out_size, void* d_ws, size_t ws_size,
                              hipStream_t stream)
{
  const float* x  = (const float*)d_in[0];
  const float* Wg = (const float*)d_in[1];
  const float* bg = (const float*)d_in[2];
  const float* W1 = (const float*)d_in[3];
  const float* b1 = (const float*)d_in[4];
  const float* W2 = (const float*)d_in[5];
  const float* b2 = (const float*)d_in[6];
  const float* W3 = (const float*)d_in[7];
  const float* b3 = (const float*)d_in[8];
  float* out = (float*)d_out;

  char* ws = (char*)d_ws;
  size_t off = 0;
  auto alloc = [&](size_t bytes) -> void* {
    void* p = ws + off;
    off = (off + bytes + 255) & ~(size_t)255;
    return p;
  };

  int*   counts    = (int*)alloc(NE * 4);
  int*   fill      = (int*)alloc(NE * 4);
  int*   offsets   = (int*)alloc((NE + 1) * 4);
  int*   tmap      = (int*)alloc(MAXTILES * 4);
  int*   eidx      = (int*)alloc((size_t)TOK * 2 * 4);
  float* gates     = (float*)alloc((size_t)TOK * 2 * 4);
  int*   slot_of   = (int*)alloc((size_t)TOK * 2 * 4);
  int*   route_tok = (int*)alloc((size_t)SLOTS * 4);
  __hip_bfloat16* Wb1 = (__hip_bfloat16*)alloc((size_t)NE * EMB  * HID  * 2);
  __hip_bfloat16* Wb2 = (__hip_bfloat16*)alloc((size_t)NE * HID  * HID2 * 2);
  __hip_bfloat16* Wb3 = (__hip_bfloat16*)alloc((size_t)NE * HID2 * EMB  * 2);
  __hip_bfloat16* xg  = (__hip_bfloat16*)alloc((size_t)(SLOTS + SLACK) * EMB  * 2);
  __hip_bfloat16* h1  = (__hip_bfloat16*)alloc((size_t)(SLOTS + SLACK) * HID  * 2);
  __hip_bfloat16* h2  = (__hip_bfloat16*)alloc((size_t)(SLOTS + SLACK) * HID2 * 2);
  float*          ybuf = (float*)alloc((size_t)(SLOTS + SLACK) * EMB * 4);
  (void)ws_size; (void)in_sizes; (void)n_in; (void)out_size;

  k_init<<<1, 64, 0, stream>>>(counts, fill);
  k_gating<<<TOK / 4, 256, 0, stream>>>(x, Wg, bg, eidx, gates, counts);
  k_offsets<<<1, 1, 0, stream>>>(counts, offsets, tmap);
  k_route<<<TOK / 256, 256, 0, stream>>>(eidx, fill, offsets, route_tok, slot_of);
  k_gather<<<SLOTS, 192, 0, stream>>>(x, route_tok, xg);

  {
    dim3 b(32, 8);
    k_transpose<<<dim3(HID  / 32, EMB  / 32, NE), b, 0, stream>>>(W1, Wb1, EMB,  HID);
    k_transpose<<<dim3(HID2 / 32, HID  / 32, NE), b, 0, stream>>>(W2, Wb2, HID,  HID2);
    k_transpose<<<dim3(EMB  / 32, HID2 / 32, NE), b, 0, stream>>>(W3, Wb3, HID2, EMB);
  }

  ffn_gemm2<true,  true ><<<dim3(HID  / 128, MAXTILES), 256, 0, stream>>>(xg, Wb1, b1, h1,   counts, offsets, tmap, EMB,  HID);
  ffn_gemm2<true,  true ><<<dim3(HID2 / 128, MAXTILES), 256, 0, stream>>>(h1, Wb2, b2, h2,   counts, offsets, tmap, HID,  HID2);
  ffn_gemm2<false, false><<<dim3(EMB  / 128, MAXTILES), 256, 0, stream>>>(h2, Wb3, b3, ybuf, counts, offsets, tmap, HID2, EMB);

  k_combine<<<TOK, 192, 0, stream>>>(ybuf, slot_of, gates, out);
}

// Round 5
// 3323.212 us; speedup vs baseline: 1.0319x; 1.0319x over previous
//
#include <hip/hip_runtime.h>
#include <hip/hip_bf16.h>

#define EMB 768
#define HID 3072
#define HID2 6144
#define NE 8
#define TOK 16384    // B*N = 8*2048
#define SLOTS 32768  // TOK * top-2
#define SLACK 256    // tail-read slack rows (M-tile 256 may overrun by 255)
#define MAXTILES 136 // max active M-tiles: 128 + (NE-1) partials; 136 = 8*17

typedef __attribute__((ext_vector_type(8))) short bf16x8;
typedef __attribute__((ext_vector_type(4))) float f32x4;

__device__ __forceinline__ unsigned short bfbits(float f) {
  __hip_bfloat16 h = __float2bfloat16(f);
  return __builtin_bit_cast(unsigned short, h);
}

// ---------------- init / gating / routing ----------------

__global__ void k_init(int* counts, int* fill) {
  if (threadIdx.x < NE) { counts[threadIdx.x] = 0; fill[threadIdx.x] = 0; }
}

__global__ __launch_bounds__(256) void k_gating(
    const float* __restrict__ x, const float* __restrict__ Wg,
    const float* __restrict__ bg, int* __restrict__ eidx,
    float* __restrict__ gates, int* __restrict__ counts)
{
  const int wave = threadIdx.x >> 6, lane = threadIdx.x & 63;
  const int t = blockIdx.x * 4 + wave;
  const float* xr = x + (size_t)t * EMB;
  float p[NE];
#pragma unroll
  for (int e = 0; e < NE; ++e) p[e] = 0.f;
  for (int k = lane; k < EMB; k += 64) {
    const float xv = xr[k];
    const float* wr = Wg + (size_t)k * NE;
#pragma unroll
    for (int e = 0; e < NE; ++e) p[e] += xv * wr[e];
  }
#pragma unroll
  for (int e = 0; e < NE; ++e) {
#pragma unroll
    for (int o = 32; o > 0; o >>= 1) p[e] += __shfl_xor(p[e], o);
    p[e] += bg[e];
  }
  float v0 = -1e30f, v1 = -1e30f; int i0 = 0, i1 = 0;
#pragma unroll
  for (int e = 0; e < NE; ++e) {
    const float v = p[e];
    if (v > v0)      { v1 = v0; i1 = i0; v0 = v; i0 = e; }
    else if (v > v1) { v1 = v;  i1 = e; }
  }
  const float ex = expf(v1 - v0);
  const float g0 = 1.f / (1.f + ex);
  const float g1 = 1.f - g0;
  if (lane == 0) {
    eidx[2*t] = i0; eidx[2*t+1] = i1;
    gates[2*t] = g0; gates[2*t+1] = g1;
    atomicAdd(&counts[i0], 1);
    atomicAdd(&counts[i1], 1);
  }
}

// offsets + compact (expert, m-tile) map so GEMM grid has ~no empty blocks
__global__ void k_offsets(const int* __restrict__ counts, int* __restrict__ offsets,
                          int* __restrict__ tmap)
{
  offsets[0] = 0;
  int idx = 0;
  for (int e = 0; e < NE; ++e) {
    offsets[e+1] = offsets[e] + counts[e];
    const int nt = (counts[e] + 255) >> 8;
    for (int i = 0; i < nt; ++i) tmap[idx++] = (e << 16) | i;
  }
  for (; idx < MAXTILES; ++idx) tmap[idx] = -1;
}

__global__ void k_route(const int* __restrict__ eidx, int* __restrict__ fill,
                        const int* __restrict__ offsets, int* __restrict__ route_tok,
                        int* __restrict__ slot_of)
{
  const int t = blockIdx.x * 256 + threadIdx.x;
  if (t >= TOK) return;
#pragma unroll
  for (int k = 0; k < 2; ++k) {
    const int e = eidx[2*t + k];
    const int pos = atomicAdd(&fill[e], 1);
    const int slot = offsets[e] + pos;
    route_tok[slot] = t;
    slot_of[2*t + k] = slot;
  }
}

__global__ void k_gather(const float* __restrict__ x, const int* __restrict__ route_tok,
                         __hip_bfloat16* __restrict__ xg)
{
  const int s = blockIdx.x;
  const int t = route_tok[s];
  const float4 v = ((const float4*)(x + (size_t)t * EMB))[threadIdx.x];
  ushort4 u;
  u.x = bfbits(v.x); u.y = bfbits(v.y); u.z = bfbits(v.z); u.w = bfbits(v.w);
  *(ushort4*)((unsigned short*)xg + (size_t)s * EMB + threadIdx.x * 4) = u;
}

// fp32 [K,N] -> bf16 [N,K]  (per expert, LDS-tiled transpose)
__global__ void k_transpose(const float* __restrict__ W, __hip_bfloat16* __restrict__ Wt,
                            int K, int N)
{
  __shared__ float tile[32][33];
  const int e = blockIdx.z;
  const float* Wp = W + (size_t)e * K * N;
  __hip_bfloat16* Wtp = Wt + (size_t)e * K * N;
  const int n0 = blockIdx.x * 32, k0 = blockIdx.y * 32;
  for (int r = threadIdx.y; r < 32; r += 8)
    tile[r][threadIdx.x] = Wp[(size_t)(k0 + r) * N + n0 + threadIdx.x];
  __syncthreads();
  for (int r = threadIdx.y; r < 32; r += 8)
    Wtp[(size_t)(n0 + r) * K + k0 + threadIdx.x] = __float2bfloat16(tile[threadIdx.x][r]);
}

// ---------------- 256x256 8-phase MFMA GEMM (K-half pipeline) ----------------
// A: bf16 [slots, K] (per-expert segments); Bt: bf16 [NE, N, K].
// BM=BN=256, BK=64, 8 waves (2M x 4N), per-wave 128x64 C.
// LDS 128 KiB = 2 slots x 64KB; slot = [A-klo|A-khi|B-klo|B-khi] 16KB halves
// (half = 256 rows x 32 cols bf16, 64B rows).
// Swizzle (R4-verified conflict-free for 64B rows): byte ^= ((row>>1)&3)<<4,
// applied on global SOURCE (linear global_load_lds dest) + ds_read addr.
// Schedule per K-tile: ph1{rd a-lo,b klo; stage A-klo(t+1)} ph2{rd a-hi klo;
// stage B-klo(t+1); vmcnt(4)} ph3{rd a-lo,b khi; stage A-khi(t+1)}
// ph4{rd a-hi khi; stage B-khi(t+1); vmcnt(4)}. All stages -> slot^1.
// Steady-state: outstanding after each vmcnt(4) is exactly the next 4 loads;
// every half has 3-4 phases of prefetch distance.
// Grid: 1-D, bijective XCD-chunk swizzle, n-panel-major within chunk -> each
// XCD's L2 holds 1-2 B-panels (<=1.5MB) across its m-tile run.

#define BARRIER() asm volatile("s_barrier" ::: "memory")

template<bool GELU, bool OUTBF>
__global__ __launch_bounds__(512) void ffn_gemm8(
    const __hip_bfloat16* __restrict__ A,
    const __hip_bfloat16* __restrict__ Bt,
    const float* __restrict__ bias,
    void* __restrict__ Cout,
    const int* __restrict__ counts,
    const int* __restrict__ offsets,
    const int* __restrict__ tmap,
    int K, int N, int nt_n)
{
  // XCD-chunked bijective swizzle; n-major inside chunk (nwg % 8 == 0 always)
  const int nwg = nt_n * MAXTILES;
  const int bid = blockIdx.x;
  const int q = nwg >> 3, r = nwg & 7;
  const int xcd = bid & 7, loc = bid >> 3;
  const int wgid = (xcd < r ? xcd * (q + 1) : r * (q + 1) + (xcd - r) * q) + loc;
  const int nidx = wgid / MAXTILES;
  const int mt   = wgid - nidx * MAXTILES;

  const int me = tmap[mt];
  if (me < 0) return;
  const int e  = me >> 16;
  const int m0 = (me & 0xffff) << 8;
  const int cnt = counts[e];
  const int seg = offsets[e];
  const int n0 = nidx * 256;

  __shared__ char lds[131072];

  const int tid = threadIdx.x;
  const int wave = tid >> 6, lane = tid & 63;
  const int wm = wave >> 2, wn = wave & 3;

  const size_t KB = (size_t)K * 2;           // global row stride bytes
  const char* Ag = (const char*)(A + (size_t)(seg + m0) * K);
  const char* Bg = (const char*)(Bt + (size_t)e * N * K + (size_t)n0 * K);

  // staging: one half = 256 rows x 64B = 2 gloads x 512thr x 16B
  const int s_r  = tid >> 2;                                    // 0..127
  const int s_cb = ((tid & 3) * 16) ^ (((s_r >> 1) & 3) << 4);  // src pre-swizzle

  auto stage_half = [&](const char* gbase, int kbyte, int ldsoff) {
    const char* s = gbase + (size_t)s_r * KB + kbyte + s_cb;
    __builtin_amdgcn_global_load_lds(
        (const __attribute__((address_space(1))) void*)s,
        (__attribute__((address_space(3))) void*)(lds + ldsoff + tid * 16), 16, 0, 0);
    __builtin_amdgcn_global_load_lds(
        (const __attribute__((address_space(1))) void*)(s + 128 * KB),
        (__attribute__((address_space(3))) void*)(lds + ldsoff + 8192 + tid * 16), 16, 0, 0);
  };

  // fragment read offsets (swizzle folded: (row>>1)&3 == (fr>>1)&3)
  const int fr    = lane & 15;
  const int coff  = ((lane >> 4) * 16) ^ (((fr >> 1) & 3) << 4);
  const int aoff0 = (wm * 128 + fr) * 64 + coff;           // + frag*1024, within A-half
  const int boff0 = 32768 + (wn * 64 + fr) * 64 + coff;    // + nf*1024, within B-half

  f32x4 acc[8][4];
#pragma unroll
  for (int i = 0; i < 8; ++i)
#pragma unroll
    for (int j = 0; j < 4; ++j)
      acc[i][j] = (f32x4){0.f, 0.f, 0.f, 0.f};

  const int KT = K >> 6;

  // ---- prologue: tile0's 4 halves -> slot0, in deadline order
  stage_half(Ag, 0, 0);          // A-klo
  stage_half(Bg, 0, 32768);      // B-klo
  stage_half(Ag, 64, 16384);     // A-khi
  stage_half(Bg, 64, 49152);     // B-khi
  asm volatile("s_waitcnt vmcnt(4)" ::: "memory");   // klo pair ready
  __builtin_amdgcn_sched_barrier(0);
  BARRIER();

  bf16x8 a[4], b[4];

  for (int kt = 0; kt < KT; ++kt) {
    const int sb  = (kt & 1) * 65536;
    const int sl1 = sb ^ 65536;
    const int kbN = (kt + 1 < KT ? kt + 1 : KT - 1) * 128;

    // ---- ph1: kh=0 m-lo ---- reads A-klo,B-klo; stage A-klo(t+1)
#pragma unroll
    for (int m = 0; m < 4; ++m)
      a[m] = *(const bf16x8*)(lds + sb + aoff0 + m * 1024);
#pragma unroll
    for (int n = 0; n < 4; ++n)
      b[n] = *(const bf16x8*)(lds + sb + boff0 + n * 1024);
    stage_half(Ag, kbN, sl1);
    BARRIER();
    asm volatile("s_waitcnt lgkmcnt(0)" ::: "memory");
    __builtin_amdgcn_sched_barrier(0);
    __builtin_amdgcn_s_setprio(1);
#pragma unroll
    for (int m = 0; m < 4; ++m)
#pragma unroll
      for (int n = 0; n < 4; ++n)
        acc[m][n] = __builtin_amdgcn_mfma_f32_16x16x32_bf16(a[m], b[n], acc[m][n], 0, 0, 0);
    __builtin_amdgcn_s_setprio(0);
    BARRIER();

    // ---- ph2: kh=0 m-hi ---- stage B-klo(t+1); drain khi(t)
#pragma unroll
    for (int m = 0; m < 4; ++m)
      a[m] = *(const bf16x8*)(lds + sb + aoff0 + (m + 4) * 1024);
    stage_half(Bg, kbN, sl1 + 32768);
    BARRIER();
    asm volatile("s_waitcnt lgkmcnt(0)" ::: "memory");
    __builtin_amdgcn_sched_barrier(0);
    __builtin_amdgcn_s_setprio(1);
#pragma unroll
    for (int m = 0; m < 4; ++m)
#pragma unroll
      for (int n = 0; n < 4; ++n)
        acc[m + 4][n] = __builtin_amdgcn_mfma_f32_16x16x32_bf16(a[m], b[n], acc[m + 4][n], 0, 0, 0);
    __builtin_amdgcn_s_setprio(0);
    asm volatile("s_waitcnt vmcnt(4)" ::: "memory");   // khi(t) ready for ph3
    __builtin_amdgcn_sched_barrier(0);
    BARRIER();

    // ---- ph3: kh=1 m-lo ---- reads A-khi,B-khi; stage A-khi(t+1)
#pragma unroll
    for (int m = 0; m < 4; ++m)
      a[m] = *(const bf16x8*)(lds + sb + 16384 + aoff0 + m * 1024);
#pragma unroll
    for (int n = 0; n < 4; ++n)
      b[n] = *(const bf16x8*)(lds + sb + 16384 + boff0 + n * 1024);
    stage_half(Ag, kbN + 64, sl1 + 16384);
    BARRIER();
    asm volatile("s_waitcnt lgkmcnt(0)" ::: "memory");
    __builtin_amdgcn_sched_barrier(0);
    __builtin_amdgcn_s_setprio(1);
#pragma unroll
    for (int m = 0; m < 4; ++m)
#pragma unroll
      for (int n = 0; n < 4; ++n)
        acc[m][n] = __builtin_amdgcn_mfma_f32_16x16x32_bf16(a[m], b[n], acc[m][n], 0, 0, 0);
    __builtin_amdgcn_s_setprio(0);
    BARRIER();

    // ---- ph4: kh=1 m-hi ---- stage B-khi(t+1); drain klo(t+1)
#pragma unroll
    for (int m = 0; m < 4; ++m)
      a[m] = *(const bf16x8*)(lds + sb + 16384 + aoff0 + (m + 4) * 1024);
    stage_half(Bg, kbN + 64, sl1 + 49152);
    BARRIER();
    asm volatile("s_waitcnt lgkmcnt(0)" ::: "memory");
    __builtin_amdgcn_sched_barrier(0);
    __builtin_amdgcn_s_setprio(1);
#pragma unroll
    for (int m = 0; m < 4; ++m)
#pragma unroll
      for (int n = 0; n < 4; ++n)
        acc[m + 4][n] = __builtin_amdgcn_mfma_f32_16x16x32_bf16(a[m], b[n], acc[m + 4][n], 0, 0, 0);
    __builtin_amdgcn_s_setprio(0);
    asm volatile("s_waitcnt vmcnt(4)" ::: "memory");   // klo(t+1) ready for next ph1
    __builtin_amdgcn_sched_barrier(0);
    BARRIER();
  }

  // ---- epilogue: C/D map col=lane&15, row=(lane>>4)*4+r  [m89-verified]
#pragma unroll
  for (int mf = 0; mf < 8; ++mf) {
    const int gmb = m0 + wm * 128 + mf * 16 + (lane >> 4) * 4;
#pragma unroll
    for (int nf = 0; nf < 4; ++nf) {
      const int gcol = n0 + wn * 64 + nf * 16 + fr;
      const float bv = bias[(size_t)e * N + gcol];
#pragma unroll
      for (int r2 = 0; r2 < 4; ++r2) {
        const int gm = gmb + r2;
        if (gm < cnt) {
          float v = acc[mf][nf][r2] + bv;
          if (GELU) v = 0.5f * v * (1.0f + erff(v * 0.70710678118654752f));
          if (OUTBF)
            ((__hip_bfloat16*)Cout)[(size_t)(seg + gm) * N + gcol] = __float2bfloat16(v);
          else
            ((float*)Cout)[(size_t)(seg + gm) * N + gcol] = v;
        }
      }
    }
  }
}

// out[t] = g0*y[slot0] + g1*y[slot1]
__global__ void k_combine(const float* __restrict__ ybuf, const int* __restrict__ slot_of,
                          const float* __restrict__ gates, float* __restrict__ out)
{
  const int t = blockIdx.x;
  const int s0 = slot_of[2*t], s1 = slot_of[2*t+1];
  const float g0 = gates[2*t], g1 = gates[2*t+1];
  const float4 a = ((const float4*)(ybuf + (size_t)s0 * EMB))[threadIdx.x];
  const float4 b = ((const float4*)(ybuf + (size_t)s1 * EMB))[threadIdx.x];
  float4 o;
  o.x = g0 * a.x + g1 * b.x;
  o.y = g0 * a.y + g1 * b.y;
  o.z = g0 * a.z + g1 * b.z;
  o.w = g0 * a.w + g1 * b.w;
  ((float4*)(out + (size_t)t * EMB))[threadIdx.x] = o;
}

// ---------------- launch ----------------

extern "C" void kernel_launch(void* const* d_in, const int* in_sizes, int n_in,
                              void* d_out, int out_size, void* d_ws, size_t ws_size,
                              hipStream_t stream)
{
  const float* x  = (const float*)d_in[0];
  const float* Wg = (const float*)d_in[1];
  const float* bg = (const float*)d_in[2];
  const float* W1 = (const float*)d_in[3];
  const float* b1 = (const float*)d_in[4];
  const float* W2 = (const float*)d_in[5];
  const float* b2 = (const float*)d_in[6];
  const float* W3 = (const float*)d_in[7];
  const float* b3 = (const float*)d_in[8];
  float* out = (float*)d_out;

  char* ws = (char*)d_ws;
  size_t off = 0;
  auto alloc = [&](size_t bytes) -> void* {
    void* p = ws + off;
    off = (off + bytes + 255) & ~(size_t)255;
    return p;
  };

  int*   counts    = (int*)alloc(NE * 4);
  int*   fill      = (int*)alloc(NE * 4);
  int*   offsets   = (int*)alloc((NE + 1) * 4);
  int*   tmap      = (int*)alloc(MAXTILES * 4);
  int*   eidx      = (int*)alloc((size_t)TOK * 2 * 4);
  float* gates     = (float*)alloc((size_t)TOK * 2 * 4);
  int*   slot_of   = (int*)alloc((size_t)TOK * 2 * 4);
  int*   route_tok = (int*)alloc((size_t)SLOTS * 4);
  __hip_bfloat16* Wb1 = (__hip_bfloat16*)alloc((size_t)NE * EMB  * HID  * 2);
  __hip_bfloat16* Wb2 = (__hip_bfloat16*)alloc((size_t)NE * HID  * HID2 * 2);
  __hip_bfloat16* Wb3 = (__hip_bfloat16*)alloc((size_t)NE * HID2 * EMB  * 2);
  __hip_bfloat16* xg  = (__hip_bfloat16*)alloc((size_t)(SLOTS + SLACK) * EMB  * 2);
  __hip_bfloat16* h1  = (__hip_bfloat16*)alloc((size_t)(SLOTS + SLACK) * HID  * 2);
  __hip_bfloat16* h2  = (__hip_bfloat16*)alloc((size_t)(SLOTS + SLACK) * HID2 * 2);
  float*          ybuf = (float*)alloc((size_t)(SLOTS + SLACK) * EMB * 4);
  (void)ws_size; (void)in_sizes; (void)n_in; (void)out_size;

  k_init<<<1, 64, 0, stream>>>(counts, fill);
  k_gating<<<TOK / 4, 256, 0, stream>>>(x, Wg, bg, eidx, gates, counts);
  k_offsets<<<1, 1, 0, stream>>>(counts, offsets, tmap);
  k_route<<<TOK / 256, 256, 0, stream>>>(eidx, fill, offsets, route_tok, slot_of);
  k_gather<<<SLOTS, 192, 0, stream>>>(x, route_tok, xg);

  {
    dim3 b(32, 8);
    k_transpose<<<dim3(HID  / 32, EMB  / 32, NE), b, 0, stream>>>(W1, Wb1, EMB,  HID);
    k_transpose<<<dim3(HID2 / 32, HID  / 32, NE), b, 0, stream>>>(W2, Wb2, HID,  HID2);
    k_transpose<<<dim3(EMB  / 32, HID2 / 32, NE), b, 0, stream>>>(W3, Wb3, HID2, EMB);
  }

  ffn_gemm8<true,  true ><<<(HID  / 256) * MAXTILES, 512, 0, stream>>>(xg, Wb1, b1, h1,   counts, offsets, tmap, EMB,  HID,  HID  / 256);
  ffn_gemm8<true,  true ><<<(HID2 / 256) * MAXTILES, 512, 0, stream>>>(h1, Wb2, b2, h2,   counts, offsets, tmap, HID,  HID2, HID2 / 256);
  ffn_gemm8<false, false><<<(EMB  / 256) * MAXTILES, 512, 0, stream>>>(h2, Wb3, b3, ybuf, counts, offsets, tmap, HID2, EMB,  EMB  / 256);

  k_combine<<<TOK, 192, 0, stream>>>(ybuf, slot_of, gates, out);
}

// Round 6
// 3203.154 us; speedup vs baseline: 1.0706x; 1.0375x over previous
//
#include <hip/hip_runtime.h>
#include <hip/hip_bf16.h>

#define EMB 768
#define HID 3072
#define HID2 6144
#define NE 8
#define TOK 16384    // B*N = 8*2048
#define SLOTS 32768  // TOK * top-2
#define SLACK 256    // tail-read slack rows (M-tile 256 may overrun by 255)
#define MAXTILES 136 // max active M-tiles: 128 + (NE-1) partials

typedef __attribute__((ext_vector_type(8))) short bf16x8;
typedef __attribute__((ext_vector_type(4))) float f32x4;

__device__ __forceinline__ unsigned short bfbits(float f) {
  __hip_bfloat16 h = __float2bfloat16(f);
  return __builtin_bit_cast(unsigned short, h);
}

// ---------------- init / gating / routing ----------------

__global__ void k_init(int* counts, int* fill) {
  if (threadIdx.x < NE) { counts[threadIdx.x] = 0; fill[threadIdx.x] = 0; }
}

__global__ __launch_bounds__(256) void k_gating(
    const float* __restrict__ x, const float* __restrict__ Wg,
    const float* __restrict__ bg, int* __restrict__ eidx,
    float* __restrict__ gates, int* __restrict__ counts)
{
  const int wave = threadIdx.x >> 6, lane = threadIdx.x & 63;
  const int t = blockIdx.x * 4 + wave;
  const float* xr = x + (size_t)t * EMB;
  float p[NE];
#pragma unroll
  for (int e = 0; e < NE; ++e) p[e] = 0.f;
  for (int k = lane; k < EMB; k += 64) {
    const float xv = xr[k];
    const float* wr = Wg + (size_t)k * NE;
#pragma unroll
    for (int e = 0; e < NE; ++e) p[e] += xv * wr[e];
  }
#pragma unroll
  for (int e = 0; e < NE; ++e) {
#pragma unroll
    for (int o = 32; o > 0; o >>= 1) p[e] += __shfl_xor(p[e], o);
    p[e] += bg[e];
  }
  float v0 = -1e30f, v1 = -1e30f; int i0 = 0, i1 = 0;
#pragma unroll
  for (int e = 0; e < NE; ++e) {
    const float v = p[e];
    if (v > v0)      { v1 = v0; i1 = i0; v0 = v; i0 = e; }
    else if (v > v1) { v1 = v;  i1 = e; }
  }
  const float ex = expf(v1 - v0);
  const float g0 = 1.f / (1.f + ex);
  const float g1 = 1.f - g0;
  if (lane == 0) {
    eidx[2*t] = i0; eidx[2*t+1] = i1;
    gates[2*t] = g0; gates[2*t+1] = g1;
    atomicAdd(&counts[i0], 1);
    atomicAdd(&counts[i1], 1);
  }
}

// offsets + compact (expert, m-tile) map so GEMM grid has ~no empty blocks
__global__ void k_offsets(const int* __restrict__ counts, int* __restrict__ offsets,
                          int* __restrict__ tmap)
{
  offsets[0] = 0;
  int idx = 0;
  for (int e = 0; e < NE; ++e) {
    offsets[e+1] = offsets[e] + counts[e];
    const int nt = (counts[e] + 255) >> 8;
    for (int i = 0; i < nt; ++i) tmap[idx++] = (e << 16) | i;
  }
  for (; idx < MAXTILES; ++idx) tmap[idx] = -1;
}

__global__ void k_route(const int* __restrict__ eidx, int* __restrict__ fill,
                        const int* __restrict__ offsets, int* __restrict__ route_tok,
                        int* __restrict__ slot_of)
{
  const int t = blockIdx.x * 256 + threadIdx.x;
  if (t >= TOK) return;
#pragma unroll
  for (int k = 0; k < 2; ++k) {
    const int e = eidx[2*t + k];
    const int pos = atomicAdd(&fill[e], 1);
    const int slot = offsets[e] + pos;
    route_tok[slot] = t;
    slot_of[2*t + k] = slot;
  }
}

__global__ void k_gather(const float* __restrict__ x, const int* __restrict__ route_tok,
                         __hip_bfloat16* __restrict__ xg)
{
  const int s = blockIdx.x;
  const int t = route_tok[s];
  const float4 v = ((const float4*)(x + (size_t)t * EMB))[threadIdx.x];
  ushort4 u;
  u.x = bfbits(v.x); u.y = bfbits(v.y); u.z = bfbits(v.z); u.w = bfbits(v.w);
  *(ushort4*)((unsigned short*)xg + (size_t)s * EMB + threadIdx.x * 4) = u;
}

// fp32 [K,N] -> bf16 [N,K]  (per expert, LDS-tiled transpose)
__global__ void k_transpose(const float* __restrict__ W, __hip_bfloat16* __restrict__ Wt,
                            int K, int N)
{
  __shared__ float tile[32][33];
  const int e = blockIdx.z;
  const float* Wp = W + (size_t)e * K * N;
  __hip_bfloat16* Wtp = Wt + (size_t)e * K * N;
  const int n0 = blockIdx.x * 32, k0 = blockIdx.y * 32;
  for (int r = threadIdx.y; r < 32; r += 8)
    tile[r][threadIdx.x] = Wp[(size_t)(k0 + r) * N + n0 + threadIdx.x];
  __syncthreads();
  for (int r = threadIdx.y; r < 32; r += 8)
    Wtp[(size_t)(n0 + r) * K + k0 + threadIdx.x] = __float2bfloat16(tile[threadIdx.x][r]);
}

// ---------------- 256x256 MFMA GEMM, K-half pipeline, 2 barriers/K-tile ----
// A: bf16 [slots, K] (per-expert segments); Bt: bf16 [NE, N, K].
// BM=BN=256, BK=64, 8 waves (2M x 4N), per-wave 128x64 C.
// LDS 128 KiB = 2 slots x 64KB; slot = [A-klo|A-khi|B-klo|B-khi] 16KB halves
// (half = 256 rows x 32 cols bf16, 64B rows).
// Swizzle (conflict-free for 64B rows, R4-verified): byte ^= ((row>>1)&3)<<4,
// on global SOURCE (linear global_load_lds dest) + ds_read addr.
// Schedule: per K-tile, 2 relaxed halves. Each half: issue 12 ds_read +
// 4 gload_lds(next tile -> other slot) + 32 MFMA with NO intra-half pins —
// compiler emits fine-grained lgkmcnt and interleaves. Only sync:
// s_waitcnt vmcnt(4) + s_barrier at each half boundary (data-arrival of the
// half needed next). Disjoint slots make this the complete hazard set.

#define BARRIER() asm volatile("s_barrier" ::: "memory")

template<bool GELU, bool OUTBF>
__global__ __launch_bounds__(512) void ffn_gemm8(
    const __hip_bfloat16* __restrict__ A,
    const __hip_bfloat16* __restrict__ Bt,
    const float* __restrict__ bias,
    void* __restrict__ Cout,
    const int* __restrict__ counts,
    const int* __restrict__ offsets,
    const int* __restrict__ tmap,
    int K, int N)
{
  const int me = tmap[blockIdx.y];
  if (me < 0) return;
  const int e  = me >> 16;
  const int m0 = (me & 0xffff) << 8;
  const int cnt = counts[e];
  const int seg = offsets[e];
  const int n0 = blockIdx.x * 256;

  __shared__ char lds[131072];

  const int tid = threadIdx.x;
  const int wave = tid >> 6, lane = tid & 63;
  const int wm = wave >> 2, wn = wave & 3;

  const size_t KB = (size_t)K * 2;           // global row stride bytes
  const char* Ag = (const char*)(A + (size_t)(seg + m0) * K);
  const char* Bg = (const char*)(Bt + (size_t)e * N * K + (size_t)n0 * K);

  // staging: one half = 256 rows x 64B = 2 gloads x 512thr x 16B
  const int s_r  = tid >> 2;                                    // 0..127
  const int s_cb = ((tid & 3) * 16) ^ (((s_r >> 1) & 3) << 4);  // src pre-swizzle

  auto stage_half = [&](const char* gbase, int kbyte, int ldsoff) {
    const char* s = gbase + (size_t)s_r * KB + kbyte + s_cb;
    __builtin_amdgcn_global_load_lds(
        (const __attribute__((address_space(1))) void*)s,
        (__attribute__((address_space(3))) void*)(lds + ldsoff + tid * 16), 16, 0, 0);
    __builtin_amdgcn_global_load_lds(
        (const __attribute__((address_space(1))) void*)(s + 128 * KB),
        (__attribute__((address_space(3))) void*)(lds + ldsoff + 8192 + tid * 16), 16, 0, 0);
  };

  // fragment read offsets (swizzle folded: (row>>1)&3 == (fr>>1)&3)
  const int fr    = lane & 15;
  const int coff  = ((lane >> 4) * 16) ^ (((fr >> 1) & 3) << 4);
  const int aoff0 = (wm * 128 + fr) * 64 + coff;           // + frag*1024, within A-half
  const int boff0 = 32768 + (wn * 64 + fr) * 64 + coff;    // + nf*1024, within B-half

  f32x4 acc[8][4];
#pragma unroll
  for (int i = 0; i < 8; ++i)
#pragma unroll
    for (int j = 0; j < 4; ++j)
      acc[i][j] = (f32x4){0.f, 0.f, 0.f, 0.f};

  const int KT = K >> 6;

  // ---- prologue: tile0's 4 halves -> slot0, in deadline order
  stage_half(Ag, 0, 0);          // A-klo
  stage_half(Bg, 0, 32768);      // B-klo
  stage_half(Ag, 64, 16384);     // A-khi
  stage_half(Bg, 64, 49152);     // B-khi
  asm volatile("s_waitcnt vmcnt(4)" ::: "memory");   // klo pair ready
  BARRIER();

  bf16x8 a[8], b[4];

  for (int kt = 0; kt < KT; ++kt) {
    const int sb  = (kt & 1) * 65536;
    const int sl1 = sb ^ 65536;
    const int kbN = (kt + 1 < KT ? kt + 1 : KT - 1) * 128;

    // ---- half 0 (kh=0): read klo frags, stage klo(t+1), MFMA — unpinned
#pragma unroll
    for (int m = 0; m < 8; ++m)
      a[m] = *(const bf16x8*)(lds + sb + aoff0 + m * 1024);
#pragma unroll
    for (int n = 0; n < 4; ++n)
      b[n] = *(const bf16x8*)(lds + sb + boff0 + n * 1024);
    stage_half(Ag, kbN, sl1);
    stage_half(Bg, kbN, sl1 + 32768);
#pragma unroll
    for (int m = 0; m < 8; ++m)
#pragma unroll
      for (int n = 0; n < 4; ++n)
        acc[m][n] = __builtin_amdgcn_mfma_f32_16x16x32_bf16(a[m], b[n], acc[m][n], 0, 0, 0);
    asm volatile("s_waitcnt vmcnt(4)" ::: "memory");   // khi(t) arrived
    BARRIER();

    // ---- half 1 (kh=1): read khi frags, stage khi(t+1), MFMA — unpinned
#pragma unroll
    for (int m = 0; m < 8; ++m)
      a[m] = *(const bf16x8*)(lds + sb + 16384 + aoff0 + m * 1024);
#pragma unroll
    for (int n = 0; n < 4; ++n)
      b[n] = *(const bf16x8*)(lds + sb + 16384 + boff0 + n * 1024);
    stage_half(Ag, kbN + 64, sl1 + 16384);
    stage_half(Bg, kbN + 64, sl1 + 49152);
#pragma unroll
    for (int m = 0; m < 8; ++m)
#pragma unroll
      for (int n = 0; n < 4; ++n)
        acc[m][n] = __builtin_amdgcn_mfma_f32_16x16x32_bf16(a[m], b[n], acc[m][n], 0, 0, 0);
    asm volatile("s_waitcnt vmcnt(4)" ::: "memory");   // klo(t+1) arrived
    BARRIER();
  }

  // ---- epilogue: C/D map col=lane&15, row=(lane>>4)*4+r  [m89-verified]
#pragma unroll
  for (int mf = 0; mf < 8; ++mf) {
    const int gmb = m0 + wm * 128 + mf * 16 + (lane >> 4) * 4;
#pragma unroll
    for (int nf = 0; nf < 4; ++nf) {
      const int gcol = n0 + wn * 64 + nf * 16 + fr;
      const float bv = bias[(size_t)e * N + gcol];
#pragma unroll
      for (int r2 = 0; r2 < 4; ++r2) {
        const int gm = gmb + r2;
        if (gm < cnt) {
          float v = acc[mf][nf][r2] + bv;
          if (GELU) v = 0.5f * v * (1.0f + erff(v * 0.70710678118654752f));
          if (OUTBF)
            ((__hip_bfloat16*)Cout)[(size_t)(seg + gm) * N + gcol] = __float2bfloat16(v);
          else
            ((float*)Cout)[(size_t)(seg + gm) * N + gcol] = v;
        }
      }
    }
  }
}

// out[t] = g0*y[slot0] + g1*y[slot1]
__global__ void k_combine(const float* __restrict__ ybuf, const int* __restrict__ slot_of,
                          const float* __restrict__ gates, float* __restrict__ out)
{
  const int t = blockIdx.x;
  const int s0 = slot_of[2*t], s1 = slot_of[2*t+1];
  const float g0 = gates[2*t], g1 = gates[2*t+1];
  const float4 a = ((const float4*)(ybuf + (size_t)s0 * EMB))[threadIdx.x];
  const float4 b = ((const float4*)(ybuf + (size_t)s1 * EMB))[threadIdx.x];
  float4 o;
  o.x = g0 * a.x + g1 * b.x;
  o.y = g0 * a.y + g1 * b.y;
  o.z = g0 * a.z + g1 * b.z;
  o.w = g0 * a.w + g1 * b.w;
  ((float4*)(out + (size_t)t * EMB))[threadIdx.x] = o;
}

// ---------------- launch ----------------

extern "C" void kernel_launch(void* const* d_in, const int* in_sizes, int n_in,
                              void* d_out, int out_size, void* d_ws, size_t ws_size,
                              hipStream_t stream)
{
  const float* x  = (const float*)d_in[0];
  const float* Wg = (const float*)d_in[1];
  const float* bg = (const float*)d_in[2];
  const float* W1 = (const float*)d_in[3];
  const float* b1 = (const float*)d_in[4];
  const float* W2 = (const float*)d_in[5];
  const float* b2 = (const float*)d_in[6];
  const float* W3 = (const float*)d_in[7];
  const float* b3 = (const float*)d_in[8];
  float* out = (float*)d_out;

  char* ws = (char*)d_ws;
  size_t off = 0;
  auto alloc = [&](size_t bytes) -> void* {
    void* p = ws + off;
    off = (off + bytes + 255) & ~(size_t)255;
    return p;
  };

  int*   counts    = (int*)alloc(NE * 4);
  int*   fill      = (int*)alloc(NE * 4);
  int*   offsets   = (int*)alloc((NE + 1) * 4);
  int*   tmap      = (int*)alloc(MAXTILES * 4);
  int*   eidx      = (int*)alloc((size_t)TOK * 2 * 4);
  float* gates     = (float*)alloc((size_t)TOK * 2 * 4);
  int*   slot_of   = (int*)alloc((size_t)TOK * 2 * 4);
  int*   route_tok = (int*)alloc((size_t)SLOTS * 4);
  __hip_bfloat16* Wb1 = (__hip_bfloat16*)alloc((size_t)NE * EMB  * HID  * 2);
  __hip_bfloat16* Wb2 = (__hip_bfloat16*)alloc((size_t)NE * HID  * HID2 * 2);
  __hip_bfloat16* Wb3 = (__hip_bfloat16*)alloc((size_t)NE * HID2 * EMB  * 2);
  __hip_bfloat16* xg  = (__hip_bfloat16*)alloc((size_t)(SLOTS + SLACK) * EMB  * 2);
  __hip_bfloat16* h1  = (__hip_bfloat16*)alloc((size_t)(SLOTS + SLACK) * HID  * 2);
  __hip_bfloat16* h2  = (__hip_bfloat16*)alloc((size_t)(SLOTS + SLACK) * HID2 * 2);
  float*          ybuf = (float*)alloc((size_t)(SLOTS + SLACK) * EMB * 4);
  (void)ws_size; (void)in_sizes; (void)n_in; (void)out_size;

  k_init<<<1, 64, 0, stream>>>(counts, fill);
  k_gating<<<TOK / 4, 256, 0, stream>>>(x, Wg, bg, eidx, gates, counts);
  k_offsets<<<1, 1, 0, stream>>>(counts, offsets, tmap);
  k_route<<<TOK / 256, 256, 0, stream>>>(eidx, fill, offsets, route_tok, slot_of);
  k_gather<<<SLOTS, 192, 0, stream>>>(x, route_tok, xg);

  {
    dim3 b(32, 8);
    k_transpose<<<dim3(HID  / 32, EMB  / 32, NE), b, 0, stream>>>(W1, Wb1, EMB,  HID);
    k_transpose<<<dim3(HID2 / 32, HID  / 32, NE), b, 0, stream>>>(W2, Wb2, HID,  HID2);
    k_transpose<<<dim3(EMB  / 32, HID2 / 32, NE), b, 0, stream>>>(W3, Wb3, HID2, EMB);
  }

  ffn_gemm8<true,  true ><<<dim3(HID  / 256, MAXTILES), 512, 0, stream>>>(xg, Wb1, b1, h1,   counts, offsets, tmap, EMB,  HID);
  ffn_gemm8<true,  true ><<<dim3(HID2 / 256, MAXTILES), 512, 0, stream>>>(h1, Wb2, b2, h2,   counts, offsets, tmap, HID,  HID2);
  ffn_gemm8<false, false><<<dim3(EMB  / 256, MAXTILES), 512, 0, stream>>>(h2, Wb3, b3, ybuf, counts, offsets, tmap, HID2, EMB);

  k_combine<<<TOK, 192, 0, stream>>>(ybuf, slot_of, gates, out);
}